// Round 3
// baseline (309.393 us; speedup 1.0000x reference)
//
#include <hip/hip_runtime.h>
#include <hip/hip_bf16.h>
#include <cstdint>

#define BS  8
#define NR  2000
#define NC  2000
#define EMB 128

#define TR  32        // rows per block tile
#define CCH 64        // columns per chunk
#define NCH 32        // ceil(2000/64)
#define NTILE 63      // ceil(2000/32) row tiles per batch
#define NCP 2048      // padded column count in colhT/collT

typedef float  f32x4  __attribute__((ext_vector_type(4)));
typedef __bf16 bf16x8 __attribute__((ext_vector_type(8)));

#define MFMA(a, b, c) __builtin_amdgcn_mfma_f32_16x16x32_bf16((a), (b), (c), 0, 0, 0)

// ---------------- Kernel 1: projections ----------------
__global__ __launch_bounds__(256) void proj_kernel(
    const float* __restrict__ row_emb, const float* __restrict__ col_emb,
    const float* __restrict__ W,
    float* __restrict__ rp, float* __restrict__ cp, float* __restrict__ sa)
{
    int tid  = threadIdx.x;
    int lane = tid & 31;
    int sub  = tid >> 5;
    long long idx = (long long)blockIdx.x * 8 + sub;   // 0..31999

    f32x4 wr = *(const f32x4*)(W + lane * 4);
    f32x4 wc = *(const f32x4*)(W + 128 + lane * 4);

    bool is_row = idx < (long long)BS * NR;
    const float* base = is_row ? (row_emb + idx * EMB)
                               : (col_emb + (idx - (long long)BS * NR) * EMB);
    f32x4 v = *(const f32x4*)(base + lane * 4);

    float d1, d2;
    if (is_row) {
        d1 = v.x * wr.x + v.y * wr.y + v.z * wr.z + v.w * wr.w;
        d2 = v.x * wc.x + v.y * wc.y + v.z * wc.z + v.w * wc.w;
    } else {
        d1 = v.x * wc.x + v.y * wc.y + v.z * wc.z + v.w * wc.w;
        d2 = 0.f;
    }
    #pragma unroll
    for (int m = 1; m < 32; m <<= 1) {
        d1 += __shfl_xor(d1, m);
        d2 += __shfl_xor(d2, m);
    }
    if (lane == 0) {
        if (is_row) {
            rp[idx] = d1;
            float s = d1 + d2;
            sa[idx] = fmaxf(s, 0.01f * s);
        } else {
            cp[idx - (long long)BS * NR] = d1;
        }
    }
}

// ---------------- Kernel 1b: per-batch max of cp ----------------
__global__ __launch_bounds__(256) void maxcp_kernel(const float* __restrict__ cp,
                                                    float* __restrict__ maxcp)
{
    int b = blockIdx.x, tid = threadIdx.x;
    float m = -1e30f;
    for (int c = tid; c < NC; c += 256) m = fmaxf(m, cp[(size_t)b * NC + c]);
    #pragma unroll
    for (int s = 1; s < 64; s <<= 1) m = fmaxf(m, __shfl_xor(m, s));
    __shared__ float sm[4];
    if ((tid & 63) == 0) sm[tid >> 6] = m;
    __syncthreads();
    if (tid == 0)
        maxcp[b] = fmaxf(fmaxf(sm[0], sm[1]), fmaxf(sm[2], sm[3]));
}

// ---------------- Kernel 1c: transpose + bf16-split col_emb ----------------
// colhT/collT[b][e][NCP c] bf16, c >= NC zero-filled.
__global__ __launch_bounds__(256) void colsplit_kernel(
    const float* __restrict__ col_emb,
    __bf16* __restrict__ colhT, __bf16* __restrict__ collT)
{
    __shared__ float tile[64][EMB + 5];
    int tid = threadIdx.x;
    int b   = blockIdx.x >> 5;
    int c0  = (blockIdx.x & 31) * 64;

    #pragma unroll
    for (int i = 0; i < 8; ++i) {
        int flat = i * 256 + tid;
        int c = flat >> 5, e = (flat & 31) * 4;
        int cg = c0 + c;
        f32x4 v = {0.f, 0.f, 0.f, 0.f};
        if (cg < NC) v = *(const f32x4*)(col_emb + ((size_t)b * NC + cg) * EMB + e);
        *(f32x4*)&tile[c][e] = v;
    }
    __syncthreads();
    #pragma unroll
    for (int i = 0; i < 8; ++i) {
        int flat = i * 256 + tid;
        int e = flat >> 4, cb = (flat & 15) * 4;
        ushort4 hv, lv;
        #pragma unroll
        for (int j = 0; j < 4; ++j) {
            float v = tile[cb + j][e];
            __bf16 h = (__bf16)v;
            float rs = v - (float)h;
            __bf16 l = (__bf16)rs;
            ((unsigned short*)&hv)[j] = __builtin_bit_cast(unsigned short, h);
            ((unsigned short*)&lv)[j] = __builtin_bit_cast(unsigned short, l);
        }
        size_t off = ((size_t)b * EMB + e) * NCP + c0 + cb;
        *(ushort4*)((unsigned short*)colhT + off) = hv;
        *(ushort4*)((unsigned short*)collT + off) = lv;
    }
}

__device__ __forceinline__ void load_cost8(const float* __restrict__ cost_row,
                                           int k, int c8, f32x4& a, f32x4& b)
{
    int cbase = k * CCH + c8 * 8;
    int cc = (cbase > NC - 8) ? (NC - 8) : cbase;
    a = *(const f32x4*)(cost_row + cc);
    b = *(const f32x4*)(cost_row + cc + 4);
}

__device__ __forceinline__ void write_tile(float* __restrict__ outb,
    const float* __restrict__ rowb, const float* ps_sm, const float* l_sm,
    int r0, int mt, int lane, int col, f32x4 acc)
{
    const int cgl = col + (lane & 15);   // D-fragment: col = lane&15 (was MISSING -> round-2 fail)
    #pragma unroll
    for (int i = 0; i < 4; ++i) {
        int row = mt * 16 + (lane >> 4) * 4 + i;   // D-fragment: row = (lane>>4)*4 + reg
        int rg  = r0 + row;
        if (rg < NR) {
            float ps  = ps_sm[row];
            float inv = 1.0f / (ps + l_sm[row]);
            float rv  = rowb[(size_t)rg * EMB + cgl];
            outb[(size_t)rg * EMB + cgl] = (acc[i] + rv * ps) * inv;
        }
    }
}

// ---------------- Kernel 2: fused softmax + split-bf16 MFMA P@col ----------------
__global__ __launch_bounds__(256) void main_kernel(
    const float* __restrict__ row_emb, const float* __restrict__ cost,
    const float* __restrict__ rp, const float* __restrict__ cp,
    const float* __restrict__ sa, const float* __restrict__ maxcp,
    const __bf16* __restrict__ colhT, const __bf16* __restrict__ collT,
    float* __restrict__ out)
{
    __shared__ __align__(16) __bf16 pbuf[2][2][TR][CCH];  // [dbuf][hi/lo][row][swz col] 16 KB
    __shared__ float cp_sm[NCP];
    __shared__ float l_sm[TR], ps_sm[TR], M_sm[TR], rp_sm[TR];

    const int tid  = threadIdx.x;
    const int bid  = (blockIdx.x & 7) * (NTILE) + (blockIdx.x >> 3); // batch->XCD
    const int b    = bid / NTILE;
    const int t    = bid % NTILE;
    const int r0   = t * TR;

    // phase-1 mapping: thread -> (row, 8-col block)
    const int p_r  = tid >> 3;                 // 0..31
    const int p_c8 = tid & 7;                  // 0..7
    const int rg1  = r0 + p_r;
    const int rc1  = (rg1 < NR) ? rg1 : (NR - 1);
    const float* cost_row = cost + ((size_t)b * NR + rc1) * NC;

    // phase-2 mapping: wave -> (m-tile, 64-wide n-group)
    const int w    = tid >> 6;
    const int lane = tid & 63;
    const int mt   = w & 1;
    const int n0w  = (w >> 1) * 64;
    const int arow = mt * 16 + (lane & 15);
    const __bf16* bh = colhT + (size_t)b * EMB * NCP;
    const __bf16* bl = collT + (size_t)b * EMB * NCP;

    // ---- prologue: stage cp, per-row constants ----
    for (int i = tid; i < NCP / 4; i += 256) {
        int src = i * 4; if (src > NC - 4) src = NC - 4;
        *(f32x4*)&cp_sm[i * 4] = *(const f32x4*)&cp[(size_t)b * NC + src];
    }
    if (tid < TR) {
        int rg = r0 + tid; int rc = (rg < NR) ? rg : (NR - 1);
        float rpv = rp[(size_t)b * NR + rc];
        float sav = sa[(size_t)b * NR + rc];
        float M   = fmaxf(fmaxf(0.f, rpv + maxcp[b]), sav);
        M_sm[tid] = M; rp_sm[tid] = rpv; ps_sm[tid] = __expf(sav - M);
    }
    f32x4 cu0, cu1;
    load_cost8(cost_row, 0, p_c8, cu0, cu1);
    __syncthreads();

    const float rp_r = rp_sm[p_r];
    const float M_r  = M_sm[p_r];

    f32x4 acc0 = {0,0,0,0}, acc1 = {0,0,0,0}, acc2 = {0,0,0,0}, acc3 = {0,0,0,0};
    float lp = 0.f;

    for (int k = 0; k < NCH; ++k) {
        // prefetch next chunk's cost (HBM latency hidden under this chunk)
        f32x4 cn0, cn1;
        load_cost8(cost_row, (k + 1 < NCH) ? k + 1 : NCH - 1, p_c8, cn0, cn1);

        // B fragments for this chunk straight from global (L2/L3-resident)
        bf16x8 Bh[2][4], Bl[2][4];
        #pragma unroll
        for (int ks = 0; ks < 2; ++ks)
            #pragma unroll
            for (int j = 0; j < 4; ++j) {
                size_t off = (size_t)(n0w + j * 16 + (lane & 15)) * NCP
                           + (size_t)k * CCH + ks * 32 + ((lane >> 4) * 8);
                Bh[ks][j] = *(const bf16x8*)(bh + off);
                Bl[ks][j] = *(const bf16x8*)(bl + off);
            }

        // ---- phase 1: P(k) -> pbuf[k&1], split hi/lo bf16 ----
        {
            f32x4 cpv0 = *(const f32x4*)&cp_sm[k * CCH + p_c8 * 8];
            f32x4 cpv1 = *(const f32x4*)&cp_sm[k * CCH + p_c8 * 8 + 4];
            bf16x8 hh, ll;
            #pragma unroll
            for (int j = 0; j < 8; ++j) {
                float cj  = (j < 4) ? cu0[j] : cu1[j - 4];
                float cpj = (j < 4) ? cpv0[j] : cpv1[j - 4];
                float logit = (rp_r + cpj) * cj;
                float act   = fmaxf(logit, 0.01f * logit);
                float pv    = __expf(act - M_r);
                int cidx = k * CCH + p_c8 * 8 + j;
                pv = (cidx < NC) ? pv : 0.0f;
                lp += pv;
                __bf16 hb = (__bf16)pv;
                hh[j] = hb;
                ll[j] = (__bf16)(pv - (float)hb);
            }
            int wslot = (p_c8 ^ (p_r & 7)) * 8;
            *(bf16x8*)&pbuf[k & 1][0][p_r][wslot] = hh;
            *(bf16x8*)&pbuf[k & 1][1][p_r][wslot] = ll;
        }

        __syncthreads();

        // ---- phase 2: A from LDS (swizzled), 24 MFMAs ----
        __builtin_amdgcn_s_setprio(1);
        #pragma unroll
        for (int ks = 0; ks < 2; ++ks) {
            int aslot = (((ks * 4) + (lane >> 4)) ^ (arow & 7)) * 8;
            bf16x8 Ah = *(const bf16x8*)&pbuf[k & 1][0][arow][aslot];
            bf16x8 Al = *(const bf16x8*)&pbuf[k & 1][1][arow][aslot];
            acc0 = MFMA(Ah, Bh[ks][0], acc0);
            acc1 = MFMA(Ah, Bh[ks][1], acc1);
            acc2 = MFMA(Ah, Bh[ks][2], acc2);
            acc3 = MFMA(Ah, Bh[ks][3], acc3);
            acc0 = MFMA(Al, Bh[ks][0], acc0);
            acc1 = MFMA(Al, Bh[ks][1], acc1);
            acc2 = MFMA(Al, Bh[ks][2], acc2);
            acc3 = MFMA(Al, Bh[ks][3], acc3);
            acc0 = MFMA(Ah, Bl[ks][0], acc0);
            acc1 = MFMA(Ah, Bl[ks][1], acc1);
            acc2 = MFMA(Ah, Bl[ks][2], acc2);
            acc3 = MFMA(Ah, Bl[ks][3], acc3);
        }
        __builtin_amdgcn_s_setprio(0);

        cu0 = cn0; cu1 = cn1;
    }

    // ---- epilogue ----
    lp += __shfl_xor(lp, 1);
    lp += __shfl_xor(lp, 2);
    lp += __shfl_xor(lp, 4);
    if (p_c8 == 0) l_sm[p_r] = lp;
    __syncthreads();

    const float* rowb = row_emb + (size_t)b * NR * EMB;
    float*       outb = out     + (size_t)b * NR * EMB;
    write_tile(outb, rowb, ps_sm, l_sm, r0, mt, lane, n0w + 0,  acc0);
    write_tile(outb, rowb, ps_sm, l_sm, r0, mt, lane, n0w + 16, acc1);
    write_tile(outb, rowb, ps_sm, l_sm, r0, mt, lane, n0w + 32, acc2);
    write_tile(outb, rowb, ps_sm, l_sm, r0, mt, lane, n0w + 48, acc3);
}

extern "C" void kernel_launch(void* const* d_in, const int* in_sizes, int n_in,
                              void* d_out, int out_size, void* d_ws, size_t ws_size,
                              hipStream_t stream) {
    const float* row_emb = (const float*)d_in[0];
    const float* col_emb = (const float*)d_in[1];
    const float* cost    = (const float*)d_in[2];
    const float* W       = (const float*)d_in[3];
    float* out = (float*)d_out;
    float* ws  = (float*)d_ws;

    float* rp = ws;            // 16000 f32
    float* sa = ws + 16000;    // 16000
    float* cp = ws + 32000;    // 16000
    float* mc = ws + 48000;    // 8
    __bf16* colhT = (__bf16*)(ws + 48064);                  // 8*128*2048 bf16 = 4 MB
    __bf16* collT = colhT + (size_t)BS * EMB * NCP;         // 4 MB

    proj_kernel<<<4000, 256, 0, stream>>>(row_emb, col_emb, W, rp, cp, sa);
    maxcp_kernel<<<BS, 256, 0, stream>>>(cp, mc);
    colsplit_kernel<<<BS * 32, 256, 0, stream>>>(col_emb, colhT, collT);
    main_kernel<<<BS * NTILE, 256, 0, stream>>>(row_emb, cost, rp, cp, sa, mc,
                                                colhT, collT, out);
}

// Round 4
// 252.027 us; speedup vs baseline: 1.2276x; 1.2276x over previous
//
#include <hip/hip_runtime.h>
#include <hip/hip_bf16.h>
#include <cstdint>

#define BS  8
#define NR  2000
#define NC  2000
#define EMB 128

#define TRB   64      // rows per block
#define NTILE 32      // ceil(2000/64)
#define NCHB  32      // 64-col chunks (2048 padded)

typedef float  f32x4  __attribute__((ext_vector_type(4)));
typedef __bf16 bf16x8 __attribute__((ext_vector_type(8)));

#define MFMA(a,b,c) __builtin_amdgcn_mfma_f32_16x16x32_bf16((a),(b),(c),0,0,0)

// ---------------- Kernel 1: projections ----------------
__global__ __launch_bounds__(256) void proj_kernel(
    const float* __restrict__ row_emb, const float* __restrict__ col_emb,
    const float* __restrict__ W,
    float* __restrict__ rp, float* __restrict__ cp, float* __restrict__ sa)
{
    int tid  = threadIdx.x;
    int lane = tid & 31;
    int sub  = tid >> 5;
    long long idx = (long long)blockIdx.x * 8 + sub;   // 0..31999

    f32x4 wr = *(const f32x4*)(W + lane * 4);
    f32x4 wc = *(const f32x4*)(W + 128 + lane * 4);

    bool is_row = idx < (long long)BS * NR;
    const float* base = is_row ? (row_emb + idx * EMB)
                               : (col_emb + (idx - (long long)BS * NR) * EMB);
    f32x4 v = *(const f32x4*)(base + lane * 4);

    float d1, d2;
    if (is_row) {
        d1 = v.x * wr.x + v.y * wr.y + v.z * wr.z + v.w * wr.w;
        d2 = v.x * wc.x + v.y * wc.y + v.z * wc.z + v.w * wc.w;
    } else {
        d1 = v.x * wc.x + v.y * wc.y + v.z * wc.z + v.w * wc.w;
        d2 = 0.f;
    }
    #pragma unroll
    for (int m = 1; m < 32; m <<= 1) {
        d1 += __shfl_xor(d1, m);
        d2 += __shfl_xor(d2, m);
    }
    if (lane == 0) {
        if (is_row) {
            rp[idx] = d1;
            float s = d1 + d2;
            sa[idx] = fmaxf(s, 0.01f * s);
        } else {
            cp[idx - (long long)BS * NR] = d1;
        }
    }
}

// ---------------- Kernel 1b: per-batch max of cp ----------------
__global__ __launch_bounds__(256) void maxcp_kernel(const float* __restrict__ cp,
                                                    float* __restrict__ maxcp)
{
    int b = blockIdx.x, tid = threadIdx.x;
    float m = -1e30f;
    for (int c = tid; c < NC; c += 256) m = fmaxf(m, cp[(size_t)b * NC + c]);
    #pragma unroll
    for (int s = 1; s < 64; s <<= 1) m = fmaxf(m, __shfl_xor(m, s));
    __shared__ float sm[4];
    if ((tid & 63) == 0) sm[tid >> 6] = m;
    __syncthreads();
    if (tid == 0)
        maxcp[b] = fmaxf(fmaxf(sm[0], sm[1]), fmaxf(sm[2], sm[3]));
}

// ---------------- Kernel 1c: build pre-swizzled colT ----------------
// colT[b][kc][hl][e 128][sp 8][8 bf16]; content at (e,sp) = cols c0+8*(sp^(e&7)),
// zero for col >= NC. Matches linear global_load_lds staging + XOR'd ds_read.
__global__ __launch_bounds__(256) void colsplit_kernel(
    const float* __restrict__ col_emb, __bf16* __restrict__ colT)
{
    __shared__ float tile[64][EMB + 4];
    int tid = threadIdx.x;
    int b   = blockIdx.x >> 5;
    int kc  = blockIdx.x & 31;
    int c0  = kc * 64;

    #pragma unroll
    for (int i = 0; i < 8; ++i) {
        int flat = i * 256 + tid;
        int c = flat >> 5, e4 = (flat & 31) * 4;
        int cg = c0 + c;
        f32x4 v = {0.f, 0.f, 0.f, 0.f};
        if (cg < NC) v = *(const f32x4*)(col_emb + ((size_t)b * NC + cg) * EMB + e4);
        *(f32x4*)&tile[c][e4] = v;
    }
    __syncthreads();
    #pragma unroll
    for (int i = 0; i < 8; ++i) {
        int flat = i * 256 + tid;          // 0..2047 = hl*1024 + e*8 + sp
        int hl = flat >> 10, e = (flat >> 3) & 127, sp = flat & 7;
        int cbase = 8 * (sp ^ (e & 7));
        bf16x8 v8;
        #pragma unroll
        for (int j = 0; j < 8; ++j) {
            float v = tile[cbase + j][e];
            __bf16 h = (__bf16)v;
            v8[j] = hl ? (__bf16)(v - (float)h) : h;
        }
        *(bf16x8*)(colT + ((size_t)(b * 32 + kc) * 16384 + (size_t)flat * 8)) = v8;
    }
}

__device__ __forceinline__ void gload16(const void* g, void* l) {
    __builtin_amdgcn_global_load_lds(
        (const __attribute__((address_space(1))) unsigned int*)g,
        (__attribute__((address_space(3))) unsigned int*)l, 16, 0, 0);
}

// ---------------- Kernel 2: fused softmax + split-bf16 MFMA P@col ----------------
__global__ __launch_bounds__(512, 2) void main_kernel(
    const float* __restrict__ row_emb, const float* __restrict__ cost,
    const float* __restrict__ rp, const float* __restrict__ cp,
    const float* __restrict__ sa, const float* __restrict__ maxcp,
    const __bf16* __restrict__ colT, float* __restrict__ out)
{
    __shared__ __align__(16) __bf16 bbuf[16384]; // [hl][n 128][sp 8][8]  32 KB
    __shared__ __align__(16) __bf16 pbuf[8192];  // [hl][m 64][sp 8][8]   16 KB
    __shared__ float cp_sm[2048];
    __shared__ float M_sm[64], rp_sm[64], ps_sm[64], l_sm[64];

    const int tid  = threadIdx.x;
    const int b    = blockIdx.x & 7;          // batch -> XCD
    const int tile = blockIdx.x >> 3;
    const int r0   = tile * TRB;

    const int w = tid >> 6, lane = tid & 63;
    const int khq = w & 1, ng = (w >> 1) & 1, mtp = w >> 2;

    const int p_row = tid >> 3, p_c8 = tid & 7;
    const int rg1 = r0 + p_row;
    const int rc1 = rg1 < NR ? rg1 : NR - 1;
    const float* cost_row = cost + ((size_t)b * NR + rc1) * NC;
    const __bf16* colTb = colT + (size_t)b * (NCHB * 16384);

    // ---- prologue ----
    if (tid < 64) {
        int rg = r0 + tid, rc = rg < NR ? rg : NR - 1;
        float rpv = rp[(size_t)b * NR + rc], sav = sa[(size_t)b * NR + rc];
        float M = fmaxf(fmaxf(0.f, rpv + maxcp[b]), sav);
        M_sm[tid] = M; rp_sm[tid] = rpv; ps_sm[tid] = __expf(sav - M);
    }
    {
        int src = tid * 4; if (src > NC - 4) src = NC - 4;
        *(f32x4*)&cp_sm[tid * 4] = *(const f32x4*)&cp[(size_t)b * NC + src];
    }

    f32x4 acc[2][4];
    #pragma unroll
    for (int i = 0; i < 2; ++i)
        #pragma unroll
        for (int j = 0; j < 4; ++j) acc[i][j] = (f32x4){0,0,0,0};
    float lp = 0.f;
    float rp_r, M_r;

    auto LC = [&](int kc, f32x4& A, f32x4& B) {
        int base = kc * 64 + p_c8 * 8;
        if (base > NC - 8) base = NC - 8;
        A = *(const f32x4*)(cost_row + base);
        B = *(const f32x4*)(cost_row + base + 4);
    };
    auto PH1 = [&](int kc, f32x4 cA, f32x4 cB) {
        int gc = kc * 64 + p_c8 * 8;
        f32x4 q0 = *(const f32x4*)&cp_sm[gc];
        f32x4 q1 = *(const f32x4*)&cp_sm[gc + 4];
        bf16x8 hh, ll;
        #pragma unroll
        for (int j = 0; j < 8; ++j) {
            float cj  = j < 4 ? cA[j] : cB[j - 4];
            float cpj = j < 4 ? q0[j] : q1[j - 4];
            float logit = (rp_r + cpj) * cj;
            float act   = fmaxf(logit, 0.01f * logit);
            float pv    = __expf(act - M_r);
            pv = (gc + j < NC) ? pv : 0.f;
            lp += pv;
            __bf16 hb = (__bf16)pv;
            hh[j] = hb;
            ll[j] = (__bf16)(pv - (float)hb);
        }
        int ws8 = (p_c8 ^ (p_row & 7)) * 8;
        *(bf16x8*)&pbuf[p_row * 64 + ws8] = hh;
        *(bf16x8*)&pbuf[4096 + p_row * 64 + ws8] = ll;
    };
    auto PH2 = [&]() {
        bf16x8 Ah[2], Al[2];
        #pragma unroll
        for (int mti = 0; mti < 2; ++mti) {
            int m = mtp * 32 + mti * 16 + (lane & 15);
            int rs = ((khq * 4 + (lane >> 4)) ^ (m & 7)) * 8;
            Ah[mti] = *(const bf16x8*)&pbuf[m * 64 + rs];
            Al[mti] = *(const bf16x8*)&pbuf[4096 + m * 64 + rs];
        }
        #pragma unroll
        for (int nf = 0; nf < 4; ++nf) {
            int n = ng * 64 + nf * 16 + (lane & 15);
            int bs = ((khq * 4 + (lane >> 4)) ^ (n & 7)) * 8;
            bf16x8 Bh = *(const bf16x8*)&bbuf[n * 64 + bs];
            bf16x8 Bl = *(const bf16x8*)&bbuf[8192 + n * 64 + bs];
            #pragma unroll
            for (int mti = 0; mti < 2; ++mti) {
                acc[mti][nf] = MFMA(Ah[mti], Bh, acc[mti][nf]);
                acc[mti][nf] = MFMA(Al[mti], Bh, acc[mti][nf]);
                acc[mti][nf] = MFMA(Ah[mti], Bl, acc[mti][nf]);
            }
        }
    };

    // stage B(0); cost(0), cost(1)
    #pragma unroll
    for (int j = 0; j < 4; ++j)
        gload16(colTb + (size_t)(j * 512 + tid) * 8, bbuf + (j * 512 + tid) * 8);
    asm volatile("" ::: "memory");
    f32x4 c00, c01; LC(0, c00, c01);
    asm volatile("" ::: "memory");
    f32x4 cc0, cc1; LC(1, cc0, cc1);
    asm volatile("" ::: "memory");
    __syncthreads();                 // cp_sm/M_sm ready; full drain incl. B(0)

    rp_r = rp_sm[p_row];
    M_r  = M_sm[p_row];

    PH1(0, c00, c01);
    asm volatile("s_waitcnt lgkmcnt(0)" ::: "memory");
    __builtin_amdgcn_s_barrier();

    for (int k = 0; k < NCHB - 1; ++k) {
        PH2();                                        // consume P(k), B(k)
        asm volatile("s_waitcnt lgkmcnt(0)" ::: "memory");
        __builtin_amdgcn_s_barrier();                 // bar A: LDS free

        const __bf16* srcB = colTb + (size_t)(k + 1) * 16384;
        #pragma unroll
        for (int j = 0; j < 4; ++j)                   // stage B(k+1): 4 vmem
            gload16(srcB + (size_t)(j * 512 + tid) * 8, bbuf + (j * 512 + tid) * 8);
        asm volatile("" ::: "memory");
        int k2 = (k + 2 < NCHB) ? k + 2 : NCHB - 1;
        f32x4 t0, t1; LC(k2, t0, t1);                 // cost(k+2): 2 vmem
        asm volatile("" ::: "memory");

        PH1(k + 1, cc0, cc1);                         // P(k+1) -> pbuf
        cc0 = t0; cc1 = t1;

        asm volatile("s_waitcnt vmcnt(2) lgkmcnt(0)" ::: "memory"); // drain stage, keep cost in flight
        __builtin_amdgcn_s_barrier();                 // bar B
    }
    PH2();                                            // chunk 31

    // ---- epilogue ----
    lp += __shfl_xor(lp, 1);
    lp += __shfl_xor(lp, 2);
    lp += __shfl_xor(lp, 4);
    if ((tid & 7) == 0) l_sm[p_row] = lp;
    __syncthreads();

    float* red = (float*)bbuf;                        // 32 KB, reuse
    if (khq == 1) {
        #pragma unroll
        for (int mti = 0; mti < 2; ++mti)
            #pragma unroll
            for (int nf = 0; nf < 4; ++nf)
                *(f32x4*)&red[(((mtp * 2 + ng) * 2 + mti) * 4 + nf) * 256 + lane * 4]
                    = acc[mti][nf];
    }
    __syncthreads();
    if (khq == 0) {
        const float* rowb = row_emb + (size_t)b * NR * EMB;
        float*       outb = out     + (size_t)b * NR * EMB;
        #pragma unroll
        for (int mti = 0; mti < 2; ++mti) {
            #pragma unroll
            for (int nf = 0; nf < 4; ++nf) {
                f32x4 o = acc[mti][nf];
                f32x4 r2 = *(const f32x4*)&red[(((mtp * 2 + ng) * 2 + mti) * 4 + nf) * 256 + lane * 4];
                o += r2;
                int col = ng * 64 + nf * 16 + (lane & 15);
                #pragma unroll
                for (int i = 0; i < 4; ++i) {
                    int row = mtp * 32 + mti * 16 + (lane >> 4) * 4 + i;
                    int rg  = r0 + row;
                    if (rg < NR) {
                        float ps  = ps_sm[row];
                        float inv = 1.0f / (ps + l_sm[row]);
                        float rv  = rowb[(size_t)rg * EMB + col];
                        outb[(size_t)rg * EMB + col] = (o[i] + rv * ps) * inv;
                    }
                }
            }
        }
    }
}

extern "C" void kernel_launch(void* const* d_in, const int* in_sizes, int n_in,
                              void* d_out, int out_size, void* d_ws, size_t ws_size,
                              hipStream_t stream) {
    const float* row_emb = (const float*)d_in[0];
    const float* col_emb = (const float*)d_in[1];
    const float* cost    = (const float*)d_in[2];
    const float* W       = (const float*)d_in[3];
    float* out = (float*)d_out;
    float* ws  = (float*)d_ws;

    float* rp = ws;            // 16000 f32
    float* sa = ws + 16000;    // 16000
    float* cp = ws + 32000;    // 16000
    float* mc = ws + 48000;    // 8
    __bf16* colT = (__bf16*)(ws + 48064);   // 8*32*16384 bf16 = 8 MB

    proj_kernel<<<4000, 256, 0, stream>>>(row_emb, col_emb, W, rp, cp, sa);
    maxcp_kernel<<<BS, 256, 0, stream>>>(cp, mc);
    colsplit_kernel<<<BS * 32, 256, 0, stream>>>(col_emb, colT);
    main_kernel<<<BS * NTILE, 512, 0, stream>>>(row_emb, cost, rp, cp, sa, mc,
                                                colT, out);
}

// Round 6
// 236.596 us; speedup vs baseline: 1.3077x; 1.0652x over previous
//
#include <hip/hip_runtime.h>
#include <hip/hip_bf16.h>
#include <cstdint>

#define BS  8
#define NR  2000
#define NC  2000
#define EMB 128

#define TRB   32      // rows per block
#define NTILE 63      // ceil(2000/32) row tiles per batch
#define NCHB  32      // 64-col chunks (2048 padded)

typedef float  f32x4  __attribute__((ext_vector_type(4)));
typedef __bf16 bf16x4 __attribute__((ext_vector_type(4)));
typedef __bf16 bf16x8 __attribute__((ext_vector_type(8)));

#define MFMA(a,b,c) __builtin_amdgcn_mfma_f32_16x16x32_bf16((a),(b),(c),0,0,0)

// ---------------- Kernel 1: projections ----------------
__global__ __launch_bounds__(256) void proj_kernel(
    const float* __restrict__ row_emb, const float* __restrict__ col_emb,
    const float* __restrict__ W,
    float* __restrict__ rp, float* __restrict__ cp, float* __restrict__ sa)
{
    int tid  = threadIdx.x;
    int lane = tid & 31;
    int sub  = tid >> 5;
    long long idx = (long long)blockIdx.x * 8 + sub;   // 0..31999

    f32x4 wr = *(const f32x4*)(W + lane * 4);
    f32x4 wc = *(const f32x4*)(W + 128 + lane * 4);

    bool is_row = idx < (long long)BS * NR;
    const float* base = is_row ? (row_emb + idx * EMB)
                               : (col_emb + (idx - (long long)BS * NR) * EMB);
    f32x4 v = *(const f32x4*)(base + lane * 4);

    float d1, d2;
    if (is_row) {
        d1 = v.x * wr.x + v.y * wr.y + v.z * wr.z + v.w * wr.w;
        d2 = v.x * wc.x + v.y * wc.y + v.z * wc.z + v.w * wc.w;
    } else {
        d1 = v.x * wc.x + v.y * wc.y + v.z * wc.z + v.w * wc.w;
        d2 = 0.f;
    }
    #pragma unroll
    for (int m = 1; m < 32; m <<= 1) {
        d1 += __shfl_xor(d1, m);
        d2 += __shfl_xor(d2, m);
    }
    if (lane == 0) {
        if (is_row) {
            rp[idx] = d1;
            float s = d1 + d2;
            sa[idx] = fmaxf(s, 0.01f * s);
        } else {
            cp[idx - (long long)BS * NR] = d1;
        }
    }
}

// ---------------- Kernel 1b: per-batch max of cp ----------------
__global__ __launch_bounds__(256) void maxcp_kernel(const float* __restrict__ cp,
                                                    float* __restrict__ maxcp)
{
    int b = blockIdx.x, tid = threadIdx.x;
    float m = -1e30f;
    for (int c = tid; c < NC; c += 256) m = fmaxf(m, cp[(size_t)b * NC + c]);
    #pragma unroll
    for (int s = 1; s < 64; s <<= 1) m = fmaxf(m, __shfl_xor(m, s));
    __shared__ float sm[4];
    if ((tid & 63) == 0) sm[tid >> 6] = m;
    __syncthreads();
    if (tid == 0)
        maxcp[b] = fmaxf(fmaxf(sm[0], sm[1]), fmaxf(sm[2], sm[3]));
}

// ---------------- Kernel 1c: build pre-swizzled colT ----------------
// colT[b][kc][hl][e 128][sp 8][8 bf16]; content at (e,sp) = cols c0+8*(sp^(e&7)),
// zero for col >= NC. Matches linear global_load_lds staging + XOR'd ds_read.
__global__ __launch_bounds__(256) void colsplit_kernel(
    const float* __restrict__ col_emb, __bf16* __restrict__ colT)
{
    __shared__ float tile[64][EMB + 4];
    int tid = threadIdx.x;
    int b   = blockIdx.x >> 5;
    int kc  = blockIdx.x & 31;
    int c0  = kc * 64;

    #pragma unroll
    for (int i = 0; i < 8; ++i) {
        int flat = i * 256 + tid;
        int c = flat >> 5, e4 = (flat & 31) * 4;
        int cg = c0 + c;
        f32x4 v = {0.f, 0.f, 0.f, 0.f};
        if (cg < NC) v = *(const f32x4*)(col_emb + ((size_t)b * NC + cg) * EMB + e4);
        *(f32x4*)&tile[c][e4] = v;
    }
    __syncthreads();
    #pragma unroll
    for (int i = 0; i < 8; ++i) {
        int flat = i * 256 + tid;          // 0..2047 = hl*1024 + e*8 + sp
        int hl = flat >> 10, e = (flat >> 3) & 127, sp = flat & 7;
        int cbase = 8 * (sp ^ (e & 7));
        bf16x8 v8;
        #pragma unroll
        for (int j = 0; j < 8; ++j) {
            float v = tile[cbase + j][e];
            __bf16 h = (__bf16)v;
            v8[j] = hl ? (__bf16)(v - (float)h) : h;
        }
        *(bf16x8*)(colT + ((size_t)(b * 32 + kc) * 16384 + (size_t)flat * 8)) = v8;
    }
}

__device__ __forceinline__ void gload16(const void* g, void* l) {
    __builtin_amdgcn_global_load_lds(
        (const __attribute__((address_space(1))) unsigned int*)g,
        (__attribute__((address_space(3))) unsigned int*)l, 16, 0, 0);
}

// ---------------- Kernel 2: fused softmax + split-bf16 MFMA P@col ----------------
// 32-row tiles, 504 blocks (~2/CU) so co-resident blocks fill each other's
// stage-latency gaps. No split-K, no extra ws buffers (round-5 overflow fix).
__global__ __launch_bounds__(512, 4) void main_kernel(
    const float* __restrict__ row_emb, const float* __restrict__ cost,
    const float* __restrict__ rp, const float* __restrict__ cp,
    const float* __restrict__ sa, const float* __restrict__ maxcp,
    const __bf16* __restrict__ colT, float* __restrict__ out)
{
    __shared__ __align__(16) __bf16 bbuf[16384]; // [hl][n 128][sp 8][8]  32 KB
    __shared__ __align__(16) __bf16 pbuf[4096];  // [hl][m 32][sp 8][8]    8 KB
    __shared__ float cp_sm[2048];
    __shared__ float M_sm[TRB], rp_sm[TRB], ps_sm[TRB], l_sm[TRB];

    const int tid  = threadIdx.x;
    const int b    = blockIdx.x & 7;          // batch -> XCD
    const int tile = blockIdx.x >> 3;         // 0..62
    const int r0   = tile * TRB;

    const int w = tid >> 6, lane = tid & 63;
    const int khq = w & 1, ng = (w >> 1) & 1, mtp = w >> 2;

    const int p_row = tid >> 4, p_c4 = tid & 15;
    const int rg1 = r0 + p_row;
    const int rc1 = rg1 < NR ? rg1 : NR - 1;
    const float* cost_row = cost + ((size_t)b * NR + rc1) * NC;
    const __bf16* colTb = colT + (size_t)b * (NCHB * 16384);

    // ---- prologue ----
    if (tid < TRB) {
        int rg = r0 + tid, rc = rg < NR ? rg : NR - 1;
        float rpv = rp[(size_t)b * NR + rc], sav = sa[(size_t)b * NR + rc];
        float M = fmaxf(fmaxf(0.f, rpv + maxcp[b]), sav);
        M_sm[tid] = M; rp_sm[tid] = rpv; ps_sm[tid] = __expf(sav - M);
    }
    {
        int src = tid * 4; if (src > NC - 4) src = NC - 4;
        *(f32x4*)&cp_sm[tid * 4] = *(const f32x4*)&cp[(size_t)b * NC + src];
    }

    f32x4 acc[4];
    #pragma unroll
    for (int j = 0; j < 4; ++j) acc[j] = (f32x4){0,0,0,0};
    float lp = 0.f;
    float rp_r, M_r;

    auto LC = [&](int kc, f32x4& A) {
        int base = kc * 64 + p_c4 * 4;
        if (base > NC - 4) base = NC - 4;
        A = *(const f32x4*)(cost_row + base);
    };
    auto PH1 = [&](int kc, f32x4 cv) {
        int gc = kc * 64 + p_c4 * 4;
        f32x4 cpq = *(const f32x4*)&cp_sm[gc];
        bf16x4 hh, ll;
        #pragma unroll
        for (int j = 0; j < 4; ++j) {
            float logit = (rp_r + cpq[j]) * cv[j];
            float act   = fmaxf(logit, 0.01f * logit);
            float pv    = __expf(act - M_r);
            pv = (gc + j < NC) ? pv : 0.f;
            lp += pv;
            __bf16 hb = (__bf16)pv;
            hh[j] = hb;
            ll[j] = (__bf16)(pv - (float)hb);
        }
        int slot = ((p_c4 >> 1) ^ (p_row & 7)) * 8 + (p_c4 & 1) * 4;
        *(bf16x4*)&pbuf[p_row * 64 + slot] = hh;
        *(bf16x4*)&pbuf[2048 + p_row * 64 + slot] = ll;
    };
    auto PH2 = [&]() {
        const int m = mtp * 16 + (lane & 15);
        const int rs = ((khq * 4 + (lane >> 4)) ^ (m & 7)) * 8;
        bf16x8 Ah = *(const bf16x8*)&pbuf[m * 64 + rs];
        bf16x8 Al = *(const bf16x8*)&pbuf[2048 + m * 64 + rs];
        __builtin_amdgcn_s_setprio(1);
        #pragma unroll
        for (int nf = 0; nf < 4; ++nf) {
            int n = ng * 64 + nf * 16 + (lane & 15);
            int bs = ((khq * 4 + (lane >> 4)) ^ (n & 7)) * 8;
            bf16x8 Bh = *(const bf16x8*)&bbuf[n * 64 + bs];
            bf16x8 Bl = *(const bf16x8*)&bbuf[8192 + n * 64 + bs];
            acc[nf] = MFMA(Ah, Bh, acc[nf]);
            acc[nf] = MFMA(Al, Bh, acc[nf]);
            acc[nf] = MFMA(Ah, Bl, acc[nf]);
        }
        __builtin_amdgcn_s_setprio(0);
    };

    // stage B(0); cost(0), cost(1)
    #pragma unroll
    for (int j = 0; j < 4; ++j)
        gload16(colTb + (size_t)(j * 512 + tid) * 8, bbuf + (j * 512 + tid) * 8);
    asm volatile("" ::: "memory");
    f32x4 c0; LC(0, c0);
    asm volatile("" ::: "memory");
    f32x4 cc; LC(1, cc);
    asm volatile("" ::: "memory");
    __syncthreads();                 // cp_sm/M_sm ready; full drain incl. B(0)

    rp_r = rp_sm[p_row];
    M_r  = M_sm[p_row];

    PH1(0, c0);
    asm volatile("s_waitcnt lgkmcnt(0)" ::: "memory");
    __builtin_amdgcn_s_barrier();

    for (int k = 0; k < NCHB - 1; ++k) {
        PH2();                                        // consume P(k), B(k)
        asm volatile("s_waitcnt lgkmcnt(0)" ::: "memory");
        __builtin_amdgcn_s_barrier();                 // bar A: LDS free

        const __bf16* srcB = colTb + (size_t)(k + 1) * 16384;
        #pragma unroll
        for (int j = 0; j < 4; ++j)                   // stage B(k+1): 4 vmem
            gload16(srcB + (size_t)(j * 512 + tid) * 8, bbuf + (j * 512 + tid) * 8);
        asm volatile("" ::: "memory");
        int k2 = (k + 2 < NCHB) ? k + 2 : NCHB - 1;
        f32x4 t; LC(k2, t);                           // cost(k+2): 1 vmem
        asm volatile("" ::: "memory");

        PH1(k + 1, cc);                               // P(k+1) -> pbuf
        cc = t;

        asm volatile("s_waitcnt vmcnt(1) lgkmcnt(0)" ::: "memory"); // drain stage, keep cost in flight
        __builtin_amdgcn_s_barrier();                 // bar B
    }
    PH2();                                            // chunk 31

    // ---- epilogue ----
    lp += __shfl_xor(lp, 1);
    lp += __shfl_xor(lp, 2);
    lp += __shfl_xor(lp, 4);
    lp += __shfl_xor(lp, 8);
    if ((tid & 15) == 0) l_sm[p_row] = lp;
    __syncthreads();

    float* red = (float*)bbuf;                        // 16 KB, reuse
    if (khq == 1) {
        #pragma unroll
        for (int nf = 0; nf < 4; ++nf)
            *(f32x4*)&red[((mtp * 2 + ng) * 4 + nf) * 256 + lane * 4] = acc[nf];
    }
    __syncthreads();
    if (khq == 0) {
        const float* rowb = row_emb + (size_t)b * NR * EMB;
        float*       outb = out     + (size_t)b * NR * EMB;
        #pragma unroll
        for (int nf = 0; nf < 4; ++nf) {
            f32x4 o = acc[nf];
            f32x4 r2 = *(const f32x4*)&red[((mtp * 2 + ng) * 4 + nf) * 256 + lane * 4];
            o += r2;
            int col = ng * 64 + nf * 16 + (lane & 15);
            #pragma unroll
            for (int i = 0; i < 4; ++i) {
                int row = mtp * 16 + (lane >> 4) * 4 + i;
                int rg  = r0 + row;
                if (rg < NR) {
                    float ps  = ps_sm[row];
                    float inv = 1.0f / (ps + l_sm[row]);
                    float rv  = rowb[(size_t)rg * EMB + col];
                    outb[(size_t)rg * EMB + col] = (o[i] + rv * ps) * inv;
                }
            }
        }
    }
}

extern "C" void kernel_launch(void* const* d_in, const int* in_sizes, int n_in,
                              void* d_out, int out_size, void* d_ws, size_t ws_size,
                              hipStream_t stream) {
    const float* row_emb = (const float*)d_in[0];
    const float* col_emb = (const float*)d_in[1];
    const float* cost    = (const float*)d_in[2];
    const float* W       = (const float*)d_in[3];
    float* out = (float*)d_out;
    float* ws  = (float*)d_ws;

    float* rp = ws;            // 16000 f32
    float* sa = ws + 16000;    // 16000
    float* cp = ws + 32000;    // 16000
    float* mc = ws + 48000;    // 8
    __bf16* colT = (__bf16*)(ws + 48064);   // 8*32*16384 bf16 = 8 MB  (total ws ~8.8 MB)

    proj_kernel<<<4000, 256, 0, stream>>>(row_emb, col_emb, W, rp, cp, sa);
    maxcp_kernel<<<BS, 256, 0, stream>>>(cp, mc);
    colsplit_kernel<<<BS * 32, 256, 0, stream>>>(col_emb, colT);
    main_kernel<<<BS * NTILE, 512, 0, stream>>>(row_emb, cost, rp, cp, sa, mc,
                                                colT, out);
}